// Round 8
// baseline (26.933 us; speedup 1.0000x reference)
//
#include <hip/hip_runtime.h>

#define MAXF 4096
#define CG 8          // channels per block

typedef float f32x4 __attribute__((ext_vector_type(4)));
typedef int   i32x4 __attribute__((ext_vector_type(4)));

// ---------------------------------------------------------------------------
// Fused, LDS-gather version. Per block = (batch b, channel-group of CG).
//  0. issue coalesced loads of the 16KB xs tile (latency hides under scan)
//  1. wave-shfl scan of ds[b,:]
//  2. stage xs tile into LDS; scatter-build idx table [0,total) in LDS
//     (+4 dummy entries at [total,total+3] for the straddling quad);
//     NO tail init — pad handled arithmetically (total<=3584<MAXF always)
//  3. stores: pad quads (p4>=total, ~56% on average) write zeros with zero
//     LDS/VALU gather work; live quads gather from LDS unconditionally;
//     only the straddling wave pays per-element masks
//  4. cg==0 block also writes pitch (idx clamped, masked by p<total) + total
// notes: nontemporal stores REGRESSED (r4); XCD swizzle NEUTRAL (r6);
//        LDS gather over global gather WIN (r7: 28.0 -> 26.2).
// ---------------------------------------------------------------------------
__global__ __launch_bounds__(512) void lr_fused(
    const float* __restrict__ xs,         // (B, C, T)
    const float* __restrict__ notepitch,  // (B, T)
    const int* __restrict__ ds,           // (B, T)
    float* __restrict__ out,              // (B, C, MAXF)
    float* __restrict__ pitch_out,        // (B, MAXF)
    float* __restrict__ total_out,        // (B,) as float
    int T, int C)
{
    const int b  = blockIdx.y;
    const int cg = blockIdx.x;
    const int t  = threadIdx.x;
    const int lane = t & 63;
    const int wid  = t >> 6;      // 0..7

    __shared__ float xtile[CG * 512];   // 16KB
    __shared__ int   idx_sh[MAXF];      // 16KB
    __shared__ int   wsum[8];

    // ---- 0. issue xs tile loads (contiguous 16KB: CG consecutive rows) ----
    const float* __restrict__ xbase = xs + ((size_t)b * C + (size_t)cg * CG) * T;
    f32x4 st0 = *reinterpret_cast<const f32x4*>(xbase + t * 4);
    f32x4 st1 = *reinterpret_cast<const f32x4*>(xbase + 2048 + t * 4);

    // ---- 1. wave-level inclusive scan of ds ----
    int v = (t < T) ? ds[b * T + t] : 0;
    int s = v;
#pragma unroll
    for (int off = 1; off < 64; off <<= 1) {
        int y = __shfl_up(s, off, 64);
        if (lane >= off) s += y;
    }
    if (lane == 63) wsum[wid] = s;
    __syncthreads();

    int woff = 0, total = 0;
#pragma unroll
    for (int w = 0; w < 8; ++w) {
        int ws = wsum[w];
        woff  += (w < wid) ? ws : 0;
        total += ws;
    }
    int cum = s + woff;           // inclusive cumsum at position t

    if (total == 0) {             // row_zero: ds -> all ones
        cum = t + 1;
        v = 1;
        total = T;
    }

    // ---- 2. stage xs tile; scatter idx [0,total); 4 dummies at total.. ----
    *reinterpret_cast<f32x4*>(&xtile[t * 4])        = st0;
    *reinterpret_cast<f32x4*>(&xtile[2048 + t * 4]) = st1;

    if (t < T && v > 0) {
        for (int p = cum - v; p < cum; ++p) idx_sh[p] = t;
    }
    if (t < 4) idx_sh[total + t] = 0;   // safe dummies for straddling quad
    __syncthreads();

    // ---- 3. stores: pad fast-path, live gather from LDS ----
    float* __restrict__ obase = out + ((size_t)b * C + (size_t)cg * CG) * MAXF;

#pragma unroll
    for (int i = 0; i < MAXF / (512 * 4); ++i) {   // 2 iterations
        const int p4 = (i * 512 + t) * 4;
        if (p4 >= total) {
            // pad region (wave-coherent): pure zero stores
            f32x4 z = {0.0f, 0.0f, 0.0f, 0.0f};
#pragma unroll
            for (int ch = 0; ch < CG; ++ch)
                *reinterpret_cast<f32x4*>(obase + (size_t)ch * MAXF + p4) = z;
        } else {
            i32x4 id = *reinterpret_cast<const i32x4*>(&idx_sh[p4]);
            if (p4 + 3 < total) {
                // fully live: unconditional gather
#pragma unroll
                for (int ch = 0; ch < CG; ++ch) {
                    const float* __restrict__ xrow = &xtile[ch * 512];
                    f32x4 vv;
                    vv.x = xrow[id.x]; vv.y = xrow[id.y];
                    vv.z = xrow[id.z]; vv.w = xrow[id.w];
                    *reinterpret_cast<f32x4*>(obase + (size_t)ch * MAXF + p4) = vv;
                }
            } else {
                // straddling quad (<=1 per block per iter): per-element mask
#pragma unroll
                for (int ch = 0; ch < CG; ++ch) {
                    const float* __restrict__ xrow = &xtile[ch * 512];
                    f32x4 vv;
                    vv.x = (p4 + 0 < total) ? xrow[id.x] : 0.0f;
                    vv.y = (p4 + 1 < total) ? xrow[id.y] : 0.0f;
                    vv.z = (p4 + 2 < total) ? xrow[id.z] : 0.0f;
                    vv.w = (p4 + 3 < total) ? xrow[id.w] : 0.0f;
                    *reinterpret_cast<f32x4*>(obase + (size_t)ch * MAXF + p4) = vv;
                }
            }
        }
    }

    // ---- 4. pitch + total (one channel-group per batch) ----
    if (cg == 0) {
        for (int p = t; p < MAXF; p += 512) {
            int id = idx_sh[p];
            id = (id < 0) ? 0 : ((id > T - 1) ? T - 1 : id);   // clamp garbage
            float pv = notepitch[b * T + id];
            pitch_out[(size_t)b * MAXF + p] = (p < total) ? pv : 0.0f;
        }
        if (t == 0) total_out[b] = (float)total;
    }
}

extern "C" void kernel_launch(void* const* d_in, const int* in_sizes, int n_in,
                              void* d_out, int out_size, void* d_ws, size_t ws_size,
                              hipStream_t stream) {
    const float* xs        = (const float*)d_in[0];
    const float* notepitch = (const float*)d_in[1];
    const int*   ds        = (const int*)d_in[2];
    // d_in[3] = x_lengths: unused by the reference computation

    const int B = in_sizes[3];
    const int T = in_sizes[1] / B;
    const int C = in_sizes[0] / (B * T);

    float* out       = (float*)d_out;
    float* pitch_out = out + (size_t)B * C * MAXF;
    float* total_out = pitch_out + (size_t)B * MAXF;

    dim3 grid(C / CG, B);
    lr_fused<<<grid, 512, 0, stream>>>(xs, notepitch, ds, out, pitch_out, total_out, T, C);
}

// Round 9
// 26.293 us; speedup vs baseline: 1.0244x; 1.0244x over previous
//
#include <hip/hip_runtime.h>

#define MAXF 4096
#define CG 4          // channels per block (r9: halved from 8 -> 2048 blocks,
                      // 2 cohorts/CU so prelude+drain overlap the store stream)

typedef float f32x4 __attribute__((ext_vector_type(4)));
typedef int   i32x4 __attribute__((ext_vector_type(4)));

// ---------------------------------------------------------------------------
// Fused, LDS-gather version (r7 structure). Per block = (batch b, cg group).
//  0. issue coalesced loads of the 8KB xs tile (latency hides under scan)
//  1. wave-shfl scan of ds[b,:]
//  2. stage xs tile into LDS; scatter-build idx table; tail [total,MAXF)=-1
//  3. gather from LDS; VMEM path carries only coalesced float4 stores
//  4. cg==0 block also writes pitch + total
// notes: nontemporal stores REGRESSED (r4); XCD swizzle NEUTRAL (r6);
//        LDS gather WIN (r7); pad-branch fast path REGRESSED (r8).
// ---------------------------------------------------------------------------
__global__ __launch_bounds__(512) void lr_fused(
    const float* __restrict__ xs,         // (B, C, T)
    const float* __restrict__ notepitch,  // (B, T)
    const int* __restrict__ ds,           // (B, T)
    float* __restrict__ out,              // (B, C, MAXF)
    float* __restrict__ pitch_out,        // (B, MAXF)
    float* __restrict__ total_out,        // (B,) as float
    int T, int C)
{
    const int b  = blockIdx.y;
    const int cg = blockIdx.x;
    const int t  = threadIdx.x;
    const int lane = t & 63;
    const int wid  = t >> 6;      // 0..7

    __shared__ float xtile[CG * 512];   // 8KB
    __shared__ int   idx_sh[MAXF];      // 16KB
    __shared__ int   wsum[8];

    // ---- 0. issue xs tile loads (contiguous 8KB: CG consecutive rows) ----
    const float* __restrict__ xbase = xs + ((size_t)b * C + (size_t)cg * CG) * T;
    f32x4 st0 = *reinterpret_cast<const f32x4*>(xbase + t * 4);

    // ---- 1. wave-level inclusive scan of ds ----
    int v = (t < T) ? ds[b * T + t] : 0;
    int s = v;
#pragma unroll
    for (int off = 1; off < 64; off <<= 1) {
        int y = __shfl_up(s, off, 64);
        if (lane >= off) s += y;
    }
    if (lane == 63) wsum[wid] = s;
    __syncthreads();

    int woff = 0, total = 0;
#pragma unroll
    for (int w = 0; w < 8; ++w) {
        int ws = wsum[w];
        woff  += (w < wid) ? ws : 0;
        total += ws;
    }
    int cum = s + woff;           // inclusive cumsum at position t

    if (total == 0) {             // row_zero: ds -> all ones
        cum = t + 1;
        v = 1;
        total = T;
    }

    // ---- 2. stage xs tile; scatter idx; tail init ----
    *reinterpret_cast<f32x4*>(&xtile[t * 4]) = st0;

    if (t < T && v > 0) {
        int hi = (cum < MAXF) ? cum : MAXF;
        for (int p = cum - v; p < hi; ++p) idx_sh[p] = t;
    }
    for (int p = total + t; p < MAXF; p += 512) idx_sh[p] = -1;
    __syncthreads();

    // ---- 3. gather from LDS + coalesced global stores ----
    float* __restrict__ obase = out + ((size_t)b * C + (size_t)cg * CG) * MAXF;

#pragma unroll
    for (int i = 0; i < MAXF / (512 * 4); ++i) {   // 2 iterations
        const int p4 = (i * 512 + t) * 4;
        i32x4 id = *reinterpret_cast<const i32x4*>(&idx_sh[p4]);
        const int jx = (id.x >= 0) ? id.x : 0;
        const int jy = (id.y >= 0) ? id.y : 0;
        const int jz = (id.z >= 0) ? id.z : 0;
        const int jw = (id.w >= 0) ? id.w : 0;
#pragma unroll
        for (int ch = 0; ch < CG; ++ch) {
            const float* __restrict__ xrow = &xtile[ch * 512];
            f32x4 vv;
            vv.x = (id.x >= 0) ? xrow[jx] : 0.0f;
            vv.y = (id.y >= 0) ? xrow[jy] : 0.0f;
            vv.z = (id.z >= 0) ? xrow[jz] : 0.0f;
            vv.w = (id.w >= 0) ? xrow[jw] : 0.0f;
            *reinterpret_cast<f32x4*>(obase + (size_t)ch * MAXF + p4) = vv;
        }
    }

    // ---- 4. pitch + total (one channel-group per batch) ----
    if (cg == 0) {
        for (int p = t; p < MAXF; p += 512) {
            int id = idx_sh[p];
            pitch_out[(size_t)b * MAXF + p] = (id >= 0) ? notepitch[b * T + id] : 0.0f;
        }
        if (t == 0) total_out[b] = (float)total;
    }
}

extern "C" void kernel_launch(void* const* d_in, const int* in_sizes, int n_in,
                              void* d_out, int out_size, void* d_ws, size_t ws_size,
                              hipStream_t stream) {
    const float* xs        = (const float*)d_in[0];
    const float* notepitch = (const float*)d_in[1];
    const int*   ds        = (const int*)d_in[2];
    // d_in[3] = x_lengths: unused by the reference computation

    const int B = in_sizes[3];
    const int T = in_sizes[1] / B;
    const int C = in_sizes[0] / (B * T);

    float* out       = (float*)d_out;
    float* pitch_out = out + (size_t)B * C * MAXF;
    float* total_out = pitch_out + (size_t)B * MAXF;

    dim3 grid(C / CG, B);
    lr_fused<<<grid, 512, 0, stream>>>(xs, notepitch, ds, out, pitch_out, total_out, T, C);
}